// Round 5
// baseline (325.375 us; speedup 1.0000x reference)
//
#include <hip/hip_runtime.h>
#include <math.h>

// ---------------------------------------------------------------------------
// AttentionNet weighted-anchor aggregator.
//   x:  (8, 448, 448, 3) f32
//   wp3:(8, 6, 4, 14, 14) f32   wp4:(8, 6, 4, 7, 7) f32   wp5:(8, 9, 4, 4, 4) f32
//   out:(32, 224, 224, 3) f32 = sum over 21 configs of
//        resize_bilinear( einsum('bkij,bihjwc->bkhwc', w, patches), 224,224 )
//
// Phase 0a: init_tables — normalized zero-padded 4-tap weights + i0.
// Phase 0b: transpose_w — weights to [cfg][b][grid][k0..k3] float4.
// Phase A : agg_all — branch-free inner loop, float2-packed (v_pk_fma_f32),
//           image-per-XCD decomposition, kwp-padded rows, uint4 stores.
// Phase B : resize_sep<CSTART,CEND> — SEPARABLE resize done per-block in LDS.
//           Block owns a 32x8 out tile; per cfg (compile-time unrolled):
//             stage A window (coalesced cooperative rows)  -> lds_a
//             vertical pass (mth taps)                     -> lds tmp strip
//             horizontal pass (mtw taps)                   -> register acc
//           Replaces the scattered per-thread 2D gathers (r1-r4 resize, the
//           ~115us half of the budget with a ~20us VALU floor) with coalesced
//           staging + (mth+mtw) separable taps.
// GROUPS  : static {0..14}, {15..18}, {19..20}; agg stays <=68MB => L3-hot.
// ---------------------------------------------------------------------------

#define BATCH 8
#define KK 4
#define OUT_HW 224
#define IMG_HW 448
#define NCFG 21

#define WTBL_BYTES (NCFG * 2 * OUT_HW * 16)     // 150528
#define ITBL_BYTES (NCFG * 2 * OUT_HW * 4)      // 37632
#define WT_OFF_BYTES (WTBL_BYTES + ITBL_BYTES)  // 188160
#define WT_F4 12912                             // 8 * (6*196 + 6*49 + 9*16)
#define AGG_OFF_BYTES (WT_OFF_BYTES + WT_F4 * 16)  // 394752 (16B aligned)

typedef float v2f __attribute__((ext_vector_type(2)));

// Compile-time cfg geometry (== host double-precision construction; margins
// to int-truncation boundaries are >=0.05 so this is exact).
static constexpr int cKH[NCFG]  = {74,60,49,93,76,62, 148,120,98,186,152,124,
                                   235,192,156,296,241,197,373,304,248};
static constexpr int cKW[NCFG]  = {49,60,74,62,76,93, 98,120,148,124,152,186,
                                   156,192,235,197,241,296,248,304,373};
static constexpr int cMTH[NCFG] = {2,2,2,2,2,2, 2,2,2,2,2,2, 3,2,2,3,3,2,4,3,3};
static constexpr int cMTW[NCFG] = {2,2,2,2,2,2, 2,2,2,2,2,2, 2,2,3,2,3,3,3,3,4};

__host__ __device__ constexpr int ckwp(int c) { return cKW[c] + (cKW[c] & 1); }
__host__ __device__ constexpr long cwsoff(int c, int g) {
    long o = 0;
    for (int k = g; k < c; ++k) o += (long)cKH[k] * ckwp(k) * (BATCH * KK);
    return o;
}
// Staged window extents for a 32x8 out tile (ceil + tap + 1 slack).
__host__ __device__ constexpr int cRmax(int c) {
    return (8 * cKH[c] + 223) / 224 + cMTH[c] + 1;
}
__host__ __device__ constexpr int cCmax(int c) {
    return (32 * cKW[c] + 223) / 224 + cMTW[c] + 1;
}

#define A_MAX 832    // >= max over cfgs of cRmax*cCmax (cfg20: 13*59=767)
#define T_W   64     // >= max cCmax (59)

struct ACfg {              // agg view of a config
    int kh, kw, kwp, p0, p1;
    int layer;             // 0=p3, 1=p4, 2=p5
    int qpr;               // pairs (2px) per row = kwp/2
    int wt_off;            // float4 offset of transposed weights
    int ws_off;            // px offset in agg region
    int block_start;
    int blocks_per_img;    // ceil(kh*qpr/256)
};

struct AggArgs {
    ACfg e[NCFG];
    int n;
};

struct TablesArgs { int kh[NCFG]; int kw[NCFG]; };

struct TrArgs {
    int layer[NCFG];
    int anchor[NCFG];
    int gsz[NCFG];
    int wt_off[NCFG];
};

struct F3 { float a, b, c; };

__device__ inline unsigned int bf16_rne(float f) {
    unsigned int u = __float_as_uint(f);
    return (u + 0x7fffu + ((u >> 16) & 1u)) >> 16;
}

// ---------------------------------------------------------------------------
// Phase 0a: tap tables. jax.image.resize('bilinear', antialias=True):
//   inv=in/out; ks=max(inv,1); sf=(o+0.5)*inv-0.5; taps i in
//   [ceil(sf-ks), floor(sf+ks)] clamped, w=max(0,1-|i-sf|/ks) normalized.
// ---------------------------------------------------------------------------
__global__ __launch_bounds__(256) void init_tables(float4* __restrict__ wtbl,
                                                   int* __restrict__ itbl,
                                                   TablesArgs t) {
    int cfg = blockIdx.x >> 1;
    int dim = blockIdx.x & 1;
    int o = threadIdx.x;
    if (o >= OUT_HW) return;
    int n = dim ? t.kw[cfg] : t.kh[cfg];

    float inv = (float)(1.0 / ((double)OUT_HW / (double)n));
    float ks  = inv > 1.f ? inv : 1.f;
    float rks = 1.f / ks;
    float sf  = ((float)o + 0.5f) * inv - 0.5f;
    int i0 = (int)ceilf(sf - ks);  if (i0 < 0) i0 = 0;
    int i1 = (int)floorf(sf + ks); if (i1 > n - 1) i1 = n - 1;
    float sum = 0.f;
    for (int i = i0; i <= i1; ++i) {
        float v = 1.f - fabsf((float)i - sf) * rks;
        sum += (v > 0.f ? v : 0.f);
    }
    float rsum = 1.f / sum;
    float w[4];
#pragma unroll
    for (int d = 0; d < 4; ++d) {
        int i = i0 + d;
        float v = 0.f;
        if (i <= i1) {
            v = 1.f - fabsf((float)i - sf) * rks;
            v = (v > 0.f ? v : 0.f) * rsum;
        }
        w[d] = v;
    }
    int idx = cfg * (2 * OUT_HW) + dim * OUT_HW + o;
    wtbl[idx] = make_float4(w[0], w[1], w[2], w[3]);
    itbl[idx] = i0;
}

// ---------------------------------------------------------------------------
// Phase 0b: transpose weights (B,A,K,gh,gw) -> per cfg [b][g][k0..k3] float4.
// ---------------------------------------------------------------------------
__global__ __launch_bounds__(256) void transpose_w(
        const float* __restrict__ wp3, const float* __restrict__ wp4,
        const float* __restrict__ wp5, float4* __restrict__ wT, TrArgs t) {
    int cfg = blockIdx.x;
    int b = blockIdx.y;
    int gsz = t.gsz[cfg];
    const float* base;
    int A;
    if (t.layer[cfg] == 0)      { base = wp3; A = 6; }
    else if (t.layer[cfg] == 1) { base = wp4; A = 6; }
    else                        { base = wp5; A = 9; }
    const float* src = base + (size_t)(b * A + t.anchor[cfg]) * (KK * gsz);
    for (int g = threadIdx.x; g < gsz; g += 256) {
        wT[t.wt_off[cfg] + b * gsz + g] =
            make_float4(src[0 * gsz + g], src[1 * gsz + g],
                        src[2 * gsz + g], src[3 * gsz + g]);
    }
}

// ---------------------------------------------------------------------------
// Agg body (templated): 2 consecutive px per thread packed as float2 lanes;
// 12 v_pk_fma_f32 per (i,j) instead of 24 scalar FMA. Branch-free: clamped
// (v_min_u32) dwordx3 loads always issue; invalid px zeroed by cndmask.
// ---------------------------------------------------------------------------
template <int GH, int GW, int STRIDE>
__device__ inline void agg_body(const ACfg& c, int b, int h, int w0,
                                const float* __restrict__ xb,
                                const float4* __restrict__ wlds,
                                uint2* __restrict__ agg) {
    v2f acc2[4][3];
#pragma unroll
    for (int k = 0; k < 4; ++k)
#pragma unroll
        for (int ch = 0; ch < 3; ++ch) { acc2[k][ch].x = 0.f; acc2[k][ch].y = 0.f; }

    const int rb = h - c.p0;
    // valid i range: 0 <= rb + i*STRIDE <= IMG_HW-1
    int ilo = rb >= 0 ? 0 : (-rb + STRIDE - 1) / STRIDE;
    int ihi = (IMG_HW - 1 - rb) / STRIDE;
    if (ihi > GH - 1) ihi = GH - 1;

    const int cb = w0 - c.p1;

#pragma unroll 1
    for (int i = ilo; i <= ihi; ++i) {
        const float* xr = xb + (size_t)(rb + i * STRIDE) * (IMG_HW * 3);
        const float4* wrow = wlds + i * GW;
#pragma unroll
        for (int j = 0; j < GW; ++j) {
            int col = cb + j * STRIDE;
            unsigned cc0 = (unsigned)col;
            if (cc0 > (unsigned)(IMG_HW - 1)) cc0 = (unsigned)(IMG_HW - 1); // v_min_u32
            unsigned cc1 = (unsigned)(col + 1);
            if (cc1 > (unsigned)(IMG_HW - 1)) cc1 = (unsigned)(IMG_HW - 1);
            F3 v0 = *(const F3*)(xr + (size_t)cc0 * 3);
            F3 v1 = *(const F3*)(xr + (size_t)cc1 * 3);
            bool k0 = (unsigned)col < (unsigned)IMG_HW;
            bool k1 = (unsigned)(col + 1) < (unsigned)IMG_HW;
            v2f d0, d1, d2;
            d0.x = k0 ? v0.a : 0.f;  d0.y = k1 ? v1.a : 0.f;
            d1.x = k0 ? v0.b : 0.f;  d1.y = k1 ? v1.b : 0.f;
            d2.x = k0 ? v0.c : 0.f;  d2.y = k1 ? v1.c : 0.f;
            float4 wk = wrow[j];   // uniform address -> broadcast b128
            v2f wv0 = {wk.x, wk.x};
            v2f wv1 = {wk.y, wk.y};
            v2f wv2 = {wk.z, wk.z};
            v2f wv3 = {wk.w, wk.w};
            acc2[0][0] = __builtin_elementwise_fma(wv0, d0, acc2[0][0]);
            acc2[0][1] = __builtin_elementwise_fma(wv0, d1, acc2[0][1]);
            acc2[0][2] = __builtin_elementwise_fma(wv0, d2, acc2[0][2]);
            acc2[1][0] = __builtin_elementwise_fma(wv1, d0, acc2[1][0]);
            acc2[1][1] = __builtin_elementwise_fma(wv1, d1, acc2[1][1]);
            acc2[1][2] = __builtin_elementwise_fma(wv1, d2, acc2[1][2]);
            acc2[2][0] = __builtin_elementwise_fma(wv2, d0, acc2[2][0]);
            acc2[2][1] = __builtin_elementwise_fma(wv2, d1, acc2[2][1]);
            acc2[2][2] = __builtin_elementwise_fma(wv2, d2, acc2[2][2]);
            acc2[3][0] = __builtin_elementwise_fma(wv3, d0, acc2[3][0]);
            acc2[3][1] = __builtin_elementwise_fma(wv3, d1, acc2[3][1]);
            acc2[3][2] = __builtin_elementwise_fma(wv3, d2, acc2[3][2]);
        }
    }

    const int npix = c.kh * c.kwp;
#pragma unroll
    for (int k = 0; k < 4; ++k) {
        size_t base = (size_t)c.ws_off + (size_t)(b * KK + k) * npix
                    + (size_t)h * c.kwp + w0;
        uint4 o;
        o.x = bf16_rne(acc2[k][0].x) | (bf16_rne(acc2[k][1].x) << 16);
        o.y = bf16_rne(acc2[k][2].x);
        o.z = bf16_rne(acc2[k][0].y) | (bf16_rne(acc2[k][1].y) << 16);
        o.w = bf16_rne(acc2[k][2].y);
        *(uint4*)(agg + base) = o;   // base even -> 16B aligned
    }
}

// ---------------------------------------------------------------------------
// Phase A: one dispatch per group; block-uniform layer switch.
// b = local & 7: with round-robin block->XCD dispatch and 8 images == 8 XCDs,
// each XCD only ever touches one image (block_start is always 8-aligned).
// ---------------------------------------------------------------------------
__global__ __launch_bounds__(256, 4) void agg_all(
        const float* __restrict__ x,
        const float4* __restrict__ wT,
        uint2* __restrict__ agg,
        AggArgs a) {
    int bid = blockIdx.x;
    int ci = 0;
    while (ci + 1 < a.n && bid >= a.e[ci + 1].block_start) ci++;
    const ACfg c = a.e[ci];
    int local = bid - c.block_start;
    int b     = local & 7;           // image-per-XCD
    int sblk  = local >> 3;

    const int gsz = (c.layer == 0) ? 196 : (c.layer == 1) ? 49 : 16;
    __shared__ float4 wlds[196];
    for (int t = threadIdx.x; t < gsz; t += 256)
        wlds[t] = wT[c.wt_off + b * gsz + t];
    __syncthreads();

    int pidx = sblk * 256 + (int)threadIdx.x;
    if (pidx >= c.kh * c.qpr) return;
    int h  = pidx / c.qpr;
    int w0 = (pidx - h * c.qpr) * 2;

    const float* __restrict__ xb = x + (size_t)b * (IMG_HW * IMG_HW * 3);
    if (c.layer == 0)      agg_body<14, 14, 32>(c, b, h, w0, xb, wlds, agg);
    else if (c.layer == 1) agg_body<7, 7, 64>(c, b, h, w0, xb, wlds, agg);
    else                   agg_body<4, 4, 128>(c, b, h, w0, xb, wlds, agg);
}

// ---------------------------------------------------------------------------
// Separable resize round (compile-time geometry). Block tile = 32x8 out px.
//   stage:  lds_a[R x CW]  <- agg window (coalesced rows, clamped)
//   V pass: tmp[8][CW]     <- mth vertical taps (weights of own out row)
//   H pass: acc            += mtw horizontal taps from tmp
// 3 barriers per round.
// ---------------------------------------------------------------------------
template <int C, int CEND, int CSTART>
__device__ inline void sep_rounds(const uint2* __restrict__ agg,
                                  const float4* __restrict__ wtbl,
                                  const int* __restrict__ itbl,
                                  uint2* __restrict__ lds_a,
                                  float (*tmpR)[T_W], float (*tmpG)[T_W],
                                  float (*tmpB)[T_W],
                                  int bk, int tx, int ty, int xo, int yo,
                                  float& a0, float& a1, float& a2) {
    if constexpr (C < CEND) {
        constexpr int kh  = cKH[C];
        constexpr int kw  = cKW[C];
        constexpr int kwp = ckwp(C);
        constexpr int mth = cMTH[C];
        constexpr int mtw = cMTW[C];
        constexpr int R   = cRmax(C);
        constexpr int CW  = cCmax(C);
        constexpr long wso = cwsoff(C, CSTART);
        const int tid = ty * 32 + tx;

        const uint2* plane = agg + wso + (size_t)bk * (kh * kwp);
        // window corners (uniform per block; L1-broadcast loads)
        const int ri0 = itbl[C * (2 * OUT_HW) + blockIdx.y * 8];
        const int ci0 = itbl[C * (2 * OUT_HW) + OUT_HW + blockIdx.x * 32];
        // own taps
        float4 wh4 = wtbl[C * (2 * OUT_HW) + yo];
        float4 ww4 = wtbl[C * (2 * OUT_HW) + OUT_HW + xo];
        const int i0 = itbl[C * (2 * OUT_HW) + yo];
        const int j0 = itbl[C * (2 * OUT_HW) + OUT_HW + xo];
        const float* wh = (const float*)&wh4;
        const float* ww = (const float*)&ww4;

        // ---- stage A window ----
#pragma unroll
        for (int p = tid; p < R * CW; p += 256) {
            int r  = p / CW;           // CW constexpr -> mul/shift
            int cc = p - r * CW;
            int gr = ri0 + r; if (gr > kh - 1) gr = kh - 1;
            int gc = ci0 + cc; if (gc > kw - 1) gc = kw - 1;
            lds_a[p] = plane[(size_t)gr * kwp + gc];
        }
        __syncthreads();

        // ---- vertical pass ----
        {
            int lr = i0 - ri0;
#pragma unroll
            for (int cc = tx; cc < CW; cc += 32) {
                float t0 = 0.f, t1 = 0.f, t2 = 0.f;
#pragma unroll
                for (int d = 0; d < mth; ++d) {
                    uint2 u = lds_a[(lr + d) * CW + cc];
                    float w = wh[d];
                    t0 = fmaf(w, __uint_as_float(u.x << 16), t0);
                    t1 = fmaf(w, __uint_as_float(u.x & 0xffff0000u), t1);
                    t2 = fmaf(w, __uint_as_float(u.y << 16), t2);
                }
                tmpR[ty][cc] = t0;
                tmpG[ty][cc] = t1;
                tmpB[ty][cc] = t2;
            }
        }
        __syncthreads();

        // ---- horizontal pass ----
        {
            int lc = j0 - ci0;
#pragma unroll
            for (int e = 0; e < mtw; ++e) {
                float w = ww[e];
                a0 = fmaf(w, tmpR[ty][lc + e], a0);
                a1 = fmaf(w, tmpG[ty][lc + e], a1);
                a2 = fmaf(w, tmpB[ty][lc + e], a2);
            }
        }
        __syncthreads();

        sep_rounds<C + 1, CEND, CSTART>(agg, wtbl, itbl, lds_a,
                                        tmpR, tmpG, tmpB,
                                        bk, tx, ty, xo, yo, a0, a1, a2);
    }
}

// ---------------------------------------------------------------------------
// Phase B: separable resize. Block = 32x8 out tile, grid (7, 28, 32).
// ---------------------------------------------------------------------------
template <int CSTART, int CEND>
__global__ __launch_bounds__(256, 4) void resize_sep(
        const uint2* __restrict__ agg,
        const float4* __restrict__ wtbl,
        const int* __restrict__ itbl,
        float* __restrict__ out,
        int accumulate) {
    const int tid = threadIdx.x;
    const int tx = tid & 31;
    const int ty = tid >> 5;
    const int xo = blockIdx.x * 32 + tx;
    const int yo = blockIdx.y * 8 + ty;
    const int bk = blockIdx.z;

    __shared__ uint2 lds_a[A_MAX];
    __shared__ float tmpR[8][T_W];
    __shared__ float tmpG[8][T_W];
    __shared__ float tmpB[8][T_W];

    size_t ob = (((size_t)bk * OUT_HW + yo) * OUT_HW + xo) * 3;
    float a0, a1, a2;
    if (accumulate) {
        a0 = out[ob]; a1 = out[ob + 1]; a2 = out[ob + 2];
    } else {
        a0 = a1 = a2 = 0.f;
    }

    sep_rounds<CSTART, CEND, CSTART>(agg, wtbl, itbl, lds_a,
                                     tmpR, tmpG, tmpB,
                                     bk, tx, ty, xo, yo, a0, a1, a2);

    out[ob + 0] = a0; out[ob + 1] = a1; out[ob + 2] = a2;
}

// ---------------------------------------------------------------------------
// Host launch
// ---------------------------------------------------------------------------
extern "C" void kernel_launch(void* const* d_in, const int* in_sizes, int n_in,
                              void* d_out, int out_size, void* d_ws, size_t ws_size,
                              hipStream_t stream) {
    const float* x   = (const float*)d_in[0];
    const float* wp3 = (const float*)d_in[1];
    const float* wp4 = (const float*)d_in[2];
    const float* wp5 = (const float*)d_in[3];
    float* out = (float*)d_out;
    float4* wtbl = (float4*)d_ws;
    int*    itbl = (int*)((char*)d_ws + WTBL_BYTES);
    float4* wT   = (float4*)((char*)d_ws + WT_OFF_BYTES);
    uint2*  agg  = (uint2*)((char*)d_ws + AGG_OFF_BYTES);

    // Build the 21 configs exactly as the reference does (double precision).
    struct { int stride, size, nscale; double scales[3]; int gh; } layers[3] = {
        {32, 48, 2, {pow(2.0, 1.0 / 3.0), pow(2.0, 2.0 / 3.0), 0.0}, 14},
        {64, 96, 2, {pow(2.0, 1.0 / 3.0), pow(2.0, 2.0 / 3.0), 0.0}, 7},
        {128, 192, 3, {1.0, pow(2.0, 1.0 / 3.0), pow(2.0, 2.0 / 3.0)}, 4},
    };
    const double ars[3] = {0.667, 1.0, 1.5};

    struct HostCfg {
        int kh, kw, kwp, stride, p0, p1, gh, gw, layer, anchor, wt_off;
        int qpr, blocks_per_img;
    } cfg[NCFG];
    TablesArgs ta;
    TrArgs tr;
    int nc = 0, wt_run = 0;
    for (int L = 0; L < 3; ++L) {
        int anchor = 0;
        for (int si = 0; si < layers[L].nscale; ++si) {
            for (int ai = 0; ai < 3; ++ai) {
                double ss = (double)layers[L].size * layers[L].scales[si];
                double sq = pow(ars[ai], 0.5);
                int kh = (int)(ss / sq);
                int kw = (int)(ss * sq);
                HostCfg& e = cfg[nc];
                e.kh = kh; e.kw = kw;
                e.kwp = kw + (kw & 1);
                e.stride = layers[L].stride;
                e.p0 = (int)ceil((double)(kh - layers[L].stride) / 2.0);
                e.p1 = (int)ceil((double)(kw - layers[L].stride) / 2.0);
                e.gh = layers[L].gh; e.gw = layers[L].gh;
                e.layer = L; e.anchor = anchor++;
                e.qpr = e.kwp / 2;
                e.blocks_per_img = (kh * e.qpr + 255) / 256;
                e.wt_off = wt_run;
                int gsz = e.gh * e.gw;
                wt_run += BATCH * gsz;
                ta.kh[nc] = kh; ta.kw[nc] = kw;
                tr.layer[nc] = L; tr.anchor[nc] = e.anchor;
                tr.gsz[nc] = gsz; tr.wt_off[nc] = e.wt_off;
                ++nc;
            }
        }
    }

    init_tables<<<NCFG * 2, 256, 0, stream>>>(wtbl, itbl, ta);
    transpose_w<<<dim3(NCFG, BATCH), 256, 0, stream>>>(wp3, wp4, wp5, wT, tr);

    dim3 rgrid(OUT_HW / 32, OUT_HW / 8, BATCH * KK);

    // Static 3-group schedule: {0..14}, {15..18}, {19..20}.
    auto build = [&](int gstart, int gend, AggArgs& aa) -> int {
        aa.n = 0;
        int ablocks = 0;
        size_t off = 0;
        for (int c = gstart; c < gend; ++c) {
            ACfg& lc = aa.e[aa.n++];
            lc.kh = cfg[c].kh; lc.kw = cfg[c].kw; lc.kwp = cfg[c].kwp;
            lc.p0 = cfg[c].p0; lc.p1 = cfg[c].p1;
            lc.layer = cfg[c].layer;
            lc.qpr = cfg[c].qpr;
            lc.wt_off = cfg[c].wt_off;
            lc.ws_off = (int)off;
            lc.block_start = ablocks;
            lc.blocks_per_img = cfg[c].blocks_per_img;
            ablocks += cfg[c].blocks_per_img * BATCH;
            off += (size_t)cfg[c].kh * cfg[c].kwp * (BATCH * KK);
        }
        return ablocks;
    };

    AggArgs aa;
    int nb;

    nb = build(0, 15, aa);
    agg_all<<<nb, 256, 0, stream>>>(x, wT, agg, aa);
    resize_sep<0, 15><<<rgrid, 256, 0, stream>>>(agg, wtbl, itbl, out, 0);

    nb = build(15, 19, aa);
    agg_all<<<nb, 256, 0, stream>>>(x, wT, agg, aa);
    resize_sep<15, 19><<<rgrid, 256, 0, stream>>>(agg, wtbl, itbl, out, 1);

    nb = build(19, 21, aa);
    agg_all<<<nb, 256, 0, stream>>>(x, wT, agg, aa);
    resize_sep<19, 21><<<rgrid, 256, 0, stream>>>(agg, wtbl, itbl, out, 1);

    (void)in_sizes; (void)n_in; (void)out_size; (void)ws_size;
}

// Round 6
// 271.858 us; speedup vs baseline: 1.1969x; 1.1969x over previous
//
#include <hip/hip_runtime.h>
#include <math.h>

// ---------------------------------------------------------------------------
// AttentionNet weighted-anchor aggregator.
//   x:  (8, 448, 448, 3) f32
//   wp3:(8, 6, 4, 14, 14) f32   wp4:(8, 6, 4, 7, 7) f32   wp5:(8, 9, 4, 4, 4) f32
//   out:(32, 224, 224, 3) f32 = sum over 21 configs of
//        resize_bilinear( einsum('bkij,bihjwc->bkhwc', w, patches), 224,224 )
//
// Phase 0a: init_tables — normalized zero-padded 4-tap weights + i0.
// Phase 0b: transpose_w — weights to [cfg][b][grid][k0..k3] float4.
// Phase A : agg_all — STRIDED-PAIR mapping: each thread owns outputs (w, w+s).
//           Output w reads cols cb+j*s; output w+s reads cb+(j+1)*s — same
//           column set shifted by one j. Thread loads GW+1 px per row i and
//           reuses each for both outputs (v_pk_fma lanes = the two outputs).
//           Halves x bytes/FMA (r4 agg was L1-BW-bound: 128B/cyc demand vs
//           64B/cyc supply -> VALU 46%). Masks/clamps hoisted (i-invariant).
//           Image-per-XCD decomposition (b = local & 7) unchanged.
// Phase B : resize_static<CSTART,CEND> — r4 taps_direct version (reverted:
//           r5's separable LDS variant moved MORE HBM traffic and regressed).
// GROUPS  : static {0..14}, {15..18}, {19..20}; agg stays <=68MB => L3-hot.
// ---------------------------------------------------------------------------

#define BATCH 8
#define KK 4
#define OUT_HW 224
#define IMG_HW 448
#define NCFG 21

#define WTBL_BYTES (NCFG * 2 * OUT_HW * 16)     // 150528
#define ITBL_BYTES (NCFG * 2 * OUT_HW * 4)      // 37632
#define WT_OFF_BYTES (WTBL_BYTES + ITBL_BYTES)  // 188160
#define WT_F4 12912                             // 8 * (6*196 + 6*49 + 9*16)
#define AGG_OFF_BYTES (WT_OFF_BYTES + WT_F4 * 16)  // 394752 (16B aligned)

typedef float v2f __attribute__((ext_vector_type(2)));

// Compile-time cfg geometry (== host double-precision construction; margins
// to int-truncation boundaries are >=0.05 so this is exact).
static constexpr int cKH[NCFG]  = {74,60,49,93,76,62, 148,120,98,186,152,124,
                                   235,192,156,296,241,197,373,304,248};
static constexpr int cKW[NCFG]  = {49,60,74,62,76,93, 98,120,148,124,152,186,
                                   156,192,235,197,241,296,248,304,373};
static constexpr int cMTH[NCFG] = {2,2,2,2,2,2, 2,2,2,2,2,2, 3,2,2,3,3,2,4,3,3};
static constexpr int cMTW[NCFG] = {2,2,2,2,2,2, 2,2,2,2,2,2, 2,2,3,2,3,3,3,3,4};

__host__ __device__ constexpr int ckwp(int c) { return cKW[c] + (cKW[c] & 1); }
__host__ __device__ constexpr long cwsoff(int c, int g) {
    long o = 0;
    for (int k = g; k < c; ++k) o += (long)cKH[k] * ckwp(k) * (BATCH * KK);
    return o;
}

struct ACfg {              // agg view of a config
    int kh, kw, kwp, p0, p1;
    int layer;             // 0=p3, 1=p4, 2=p5
    int ns;                // base-slot count per row (strided pairing)
    int wt_off;            // float4 offset of transposed weights
    int ws_off;            // px offset in agg region
    int block_start;
    int blocks_per_img;    // ceil(kh*ns/256)
};

struct AggArgs {
    ACfg e[NCFG];
    int n;
};

struct TablesArgs { int kh[NCFG]; int kw[NCFG]; };

struct TrArgs {
    int layer[NCFG];
    int anchor[NCFG];
    int gsz[NCFG];
    int wt_off[NCFG];
};

struct F3 { float a, b, c; };

__device__ inline unsigned int bf16_rne(float f) {
    unsigned int u = __float_as_uint(f);
    return (u + 0x7fffu + ((u >> 16) & 1u)) >> 16;
}

// ---------------------------------------------------------------------------
// Phase 0a: tap tables. jax.image.resize('bilinear', antialias=True):
//   inv=in/out; ks=max(inv,1); sf=(o+0.5)*inv-0.5; taps i in
//   [ceil(sf-ks), floor(sf+ks)] clamped, w=max(0,1-|i-sf|/ks) normalized.
// ---------------------------------------------------------------------------
__global__ __launch_bounds__(256) void init_tables(float4* __restrict__ wtbl,
                                                   int* __restrict__ itbl,
                                                   TablesArgs t) {
    int cfg = blockIdx.x >> 1;
    int dim = blockIdx.x & 1;
    int o = threadIdx.x;
    if (o >= OUT_HW) return;
    int n = dim ? t.kw[cfg] : t.kh[cfg];

    float inv = (float)(1.0 / ((double)OUT_HW / (double)n));
    float ks  = inv > 1.f ? inv : 1.f;
    float rks = 1.f / ks;
    float sf  = ((float)o + 0.5f) * inv - 0.5f;
    int i0 = (int)ceilf(sf - ks);  if (i0 < 0) i0 = 0;
    int i1 = (int)floorf(sf + ks); if (i1 > n - 1) i1 = n - 1;
    float sum = 0.f;
    for (int i = i0; i <= i1; ++i) {
        float v = 1.f - fabsf((float)i - sf) * rks;
        sum += (v > 0.f ? v : 0.f);
    }
    float rsum = 1.f / sum;
    float w[4];
#pragma unroll
    for (int d = 0; d < 4; ++d) {
        int i = i0 + d;
        float v = 0.f;
        if (i <= i1) {
            v = 1.f - fabsf((float)i - sf) * rks;
            v = (v > 0.f ? v : 0.f) * rsum;
        }
        w[d] = v;
    }
    int idx = cfg * (2 * OUT_HW) + dim * OUT_HW + o;
    wtbl[idx] = make_float4(w[0], w[1], w[2], w[3]);
    itbl[idx] = i0;
}

// ---------------------------------------------------------------------------
// Phase 0b: transpose weights (B,A,K,gh,gw) -> per cfg [b][g][k0..k3] float4.
// ---------------------------------------------------------------------------
__global__ __launch_bounds__(256) void transpose_w(
        const float* __restrict__ wp3, const float* __restrict__ wp4,
        const float* __restrict__ wp5, float4* __restrict__ wT, TrArgs t) {
    int cfg = blockIdx.x;
    int b = blockIdx.y;
    int gsz = t.gsz[cfg];
    const float* base;
    int A;
    if (t.layer[cfg] == 0)      { base = wp3; A = 6; }
    else if (t.layer[cfg] == 1) { base = wp4; A = 6; }
    else                        { base = wp5; A = 9; }
    const float* src = base + (size_t)(b * A + t.anchor[cfg]) * (KK * gsz);
    for (int g = threadIdx.x; g < gsz; g += 256) {
        wT[t.wt_off[cfg] + b * gsz + g] =
            make_float4(src[0 * gsz + g], src[1 * gsz + g],
                        src[2 * gsz + g], src[3 * gsz + g]);
    }
}

// ---------------------------------------------------------------------------
// Agg body: strided-pair outputs (w0, w0+STRIDE) packed as v2f lanes.
// Per row i: GW+1 clamped px loads (i-invariant offsets/masks), then GW
// j-steps of 12 v_pk_fma consuming (px[j], px[j+1]).
// ---------------------------------------------------------------------------
template <int GH, int GW, int STRIDE, int L2S>
__device__ inline void agg_body(const ACfg& c, int b, int h, int slot,
                                const float* __restrict__ xb,
                                const float4* __restrict__ wlds,
                                uint2* __restrict__ agg) {
    const int w0 = (((slot >> L2S) << (L2S + 1)) | (slot & (STRIDE - 1)));
    const int w1 = w0 + STRIDE;
    const bool two = w1 < c.kw;

    v2f acc2[4][3];
#pragma unroll
    for (int k = 0; k < 4; ++k)
#pragma unroll
        for (int ch = 0; ch < 3; ++ch) { acc2[k][ch].x = 0.f; acc2[k][ch].y = 0.f; }

    const int rb = h - c.p0;
    int ilo = rb >= 0 ? 0 : (-rb + STRIDE - 1) / STRIDE;
    int ihi = (IMG_HW - 1 - rb) / STRIDE;
    if (ihi > GH - 1) ihi = GH - 1;

    const int cb = w0 - c.p1;

    // i-invariant column offsets + validity masks
    int  cof[GW + 1];
    bool ok [GW + 1];
#pragma unroll
    for (int jj = 0; jj <= GW; ++jj) {
        int col = cb + jj * STRIDE;
        ok[jj] = (unsigned)col < (unsigned)IMG_HW;
        unsigned cc = (unsigned)col;
        if (cc > (unsigned)(IMG_HW - 1)) cc = (unsigned)(IMG_HW - 1);
        cof[jj] = (int)cc * 3;
    }

#pragma unroll 1
    for (int i = ilo; i <= ihi; ++i) {
        const float* xr = xb + (size_t)(rb + i * STRIDE) * (IMG_HW * 3);
        const float4* wrow = wlds + i * GW;

        float px[GW + 1][3];
#pragma unroll
        for (int jj = 0; jj <= GW; ++jj) {
            F3 v = *(const F3*)(xr + cof[jj]);
            px[jj][0] = ok[jj] ? v.a : 0.f;
            px[jj][1] = ok[jj] ? v.b : 0.f;
            px[jj][2] = ok[jj] ? v.c : 0.f;
        }

#pragma unroll
        for (int j = 0; j < GW; ++j) {
            float4 wk = wrow[j];
            v2f d0 = {px[j][0], px[j + 1][0]};
            v2f d1 = {px[j][1], px[j + 1][1]};
            v2f d2 = {px[j][2], px[j + 1][2]};
            v2f wv0 = {wk.x, wk.x};
            v2f wv1 = {wk.y, wk.y};
            v2f wv2 = {wk.z, wk.z};
            v2f wv3 = {wk.w, wk.w};
            acc2[0][0] = __builtin_elementwise_fma(wv0, d0, acc2[0][0]);
            acc2[0][1] = __builtin_elementwise_fma(wv0, d1, acc2[0][1]);
            acc2[0][2] = __builtin_elementwise_fma(wv0, d2, acc2[0][2]);
            acc2[1][0] = __builtin_elementwise_fma(wv1, d0, acc2[1][0]);
            acc2[1][1] = __builtin_elementwise_fma(wv1, d1, acc2[1][1]);
            acc2[1][2] = __builtin_elementwise_fma(wv1, d2, acc2[1][2]);
            acc2[2][0] = __builtin_elementwise_fma(wv2, d0, acc2[2][0]);
            acc2[2][1] = __builtin_elementwise_fma(wv2, d1, acc2[2][1]);
            acc2[2][2] = __builtin_elementwise_fma(wv2, d2, acc2[2][2]);
            acc2[3][0] = __builtin_elementwise_fma(wv3, d0, acc2[3][0]);
            acc2[3][1] = __builtin_elementwise_fma(wv3, d1, acc2[3][1]);
            acc2[3][2] = __builtin_elementwise_fma(wv3, d2, acc2[3][2]);
        }
    }

    const int npix = c.kh * c.kwp;
#pragma unroll
    for (int k = 0; k < 4; ++k) {
        size_t base = (size_t)c.ws_off + (size_t)(b * KK + k) * npix
                    + (size_t)h * c.kwp + w0;
        uint2 o0;
        o0.x = bf16_rne(acc2[k][0].x) | (bf16_rne(acc2[k][1].x) << 16);
        o0.y = bf16_rne(acc2[k][2].x);
        agg[base] = o0;
        if (two) {
            uint2 o1;
            o1.x = bf16_rne(acc2[k][0].y) | (bf16_rne(acc2[k][1].y) << 16);
            o1.y = bf16_rne(acc2[k][2].y);
            agg[base + STRIDE] = o1;
        }
    }
}

// ---------------------------------------------------------------------------
// Phase A: one dispatch per group; block-uniform layer switch.
// b = local & 7: with round-robin block->XCD dispatch and 8 images == 8 XCDs,
// each XCD only ever touches one image (block_start is always 8-aligned).
// ---------------------------------------------------------------------------
__global__ __launch_bounds__(256, 3) void agg_all(
        const float* __restrict__ x,
        const float4* __restrict__ wT,
        uint2* __restrict__ agg,
        AggArgs a) {
    int bid = blockIdx.x;
    int ci = 0;
    while (ci + 1 < a.n && bid >= a.e[ci + 1].block_start) ci++;
    const ACfg c = a.e[ci];
    int local = bid - c.block_start;
    int b     = local & 7;           // image-per-XCD
    int sblk  = local >> 3;

    const int gsz = (c.layer == 0) ? 196 : (c.layer == 1) ? 49 : 16;
    __shared__ float4 wlds[196];
    for (int t = threadIdx.x; t < gsz; t += 256)
        wlds[t] = wT[c.wt_off + b * gsz + t];
    __syncthreads();

    int pidx = sblk * 256 + (int)threadIdx.x;
    if (pidx >= c.kh * c.ns) return;
    int h    = pidx / c.ns;
    int slot = pidx - h * c.ns;

    const float* __restrict__ xb = x + (size_t)b * (IMG_HW * IMG_HW * 3);
    if (c.layer == 0)      agg_body<14, 14, 32, 5>(c, b, h, slot, xb, wlds, agg);
    else if (c.layer == 1) agg_body<7, 7, 64, 6>(c, b, h, slot, xb, wlds, agg);
    else                   agg_body<4, 4, 128, 7>(c, b, h, slot, xb, wlds, agg);
}

// ---------------------------------------------------------------------------
// Compile-time tap micro-kernel: TH x TW taps, constexpr plane geometry.
// ---------------------------------------------------------------------------
template <int TH, int TW, int KH_, int KW_, int KWP_>
__device__ inline void taps_ct(const uint2* __restrict__ base,
                               int i0, int j0,
                               float4 wh4, float4 ww4,
                               float& a0, float& a1, float& a2) {
    const float* wh = (const float*)&wh4;
    const float* ww = (const float*)&ww4;
    uint2 v[TH][TW];
#pragma unroll
    for (int d = 0; d < TH; ++d) {
        int gi = i0 + d;
        if (gi > KH_ - 1) gi = KH_ - 1;
        const uint2* rp = base + (size_t)gi * KWP_;
#pragma unroll
        for (int e = 0; e < TW; ++e) {
            int gj = j0 + e;
            if (gj > KW_ - 1) gj = KW_ - 1;
            v[d][e] = rp[gj];
        }
    }
#pragma unroll
    for (int d = 0; d < TH; ++d) {
        float r0 = 0.f, r1 = 0.f, r2 = 0.f;
#pragma unroll
        for (int e = 0; e < TW; ++e) {
            uint2 t = v[d][e];
            float c0 = __uint_as_float(t.x << 16);
            float c1 = __uint_as_float(t.x & 0xffff0000u);
            float c2 = __uint_as_float(t.y << 16);
            float w = ww[e];
            r0 = fmaf(w, c0, r0);
            r1 = fmaf(w, c1, r1);
            r2 = fmaf(w, c2, r2);
        }
        a0 = fmaf(wh[d], r0, a0);
        a1 = fmaf(wh[d], r1, a1);
        a2 = fmaf(wh[d], r2, a2);
    }
}

// ---------------------------------------------------------------------------
// if-constexpr recursion over the group's cfgs — fully unrolled rounds.
// ---------------------------------------------------------------------------
template <int C, int CEND, int CSTART>
__device__ inline void do_rounds(const uint2* __restrict__ agg,
                                 const float4* __restrict__ wlds,
                                 const int* __restrict__ ilds,
                                 int bk, int tx, int ty,
                                 float& a0, float& a1, float& a2) {
    if constexpr (C < CEND) {
        constexpr int li  = C - CSTART;
        constexpr int kh  = cKH[C];
        constexpr int kw  = cKW[C];
        constexpr int kwp = ckwp(C);
        constexpr long wso = cwsoff(C, CSTART);
        float4 wh4 = wlds[li * 32 + ty];
        float4 ww4 = wlds[li * 32 + 16 + tx];
        int i0 = ilds[li * 32 + ty];
        int j0 = ilds[li * 32 + 16 + tx];
        const uint2* plane = agg + wso + (size_t)bk * (kh * kwp);
        taps_ct<cMTH[C], cMTW[C], kh, kw, kwp>(plane, i0, j0, wh4, ww4,
                                               a0, a1, a2);
        do_rounds<C + 1, CEND, CSTART>(agg, wlds, ilds, bk, tx, ty,
                                       a0, a1, a2);
    }
}

// ---------------------------------------------------------------------------
// Phase B: static resize. One output px per thread, z = bk (32). Tables in
// LDS (one barrier), all cfg rounds compile-time unrolled.
// ---------------------------------------------------------------------------
template <int CSTART, int CEND>
__global__ __launch_bounds__(256, 4) void resize_static(
        const uint2* __restrict__ agg,
        const float4* __restrict__ wtbl,
        const int* __restrict__ itbl,
        float* __restrict__ out,
        int accumulate) {
    constexpr int NC = CEND - CSTART;
    const int tid = threadIdx.x;
    const int tx = tid & 15;
    const int ty = tid >> 4;
    const int xo = blockIdx.x * 16 + tx;
    const int yo = blockIdx.y * 16 + ty;
    const int bk = blockIdx.z;

    __shared__ float4 wlds[NC * 32];
    __shared__ int    ilds[NC * 32];

    for (int e = tid; e < NC * 32; e += 256) {
        int ci  = e >> 5;
        int r   = e & 31;
        int isW = r >> 4;
        int idx = r & 15;
        int base_o = isW ? (blockIdx.x * 16) : (blockIdx.y * 16);
        int src = (CSTART + ci) * (2 * OUT_HW) + isW * OUT_HW + base_o + idx;
        wlds[ci * 32 + r] = wtbl[src];
        ilds[ci * 32 + r] = itbl[src];
    }
    __syncthreads();

    size_t ob = (((size_t)bk * OUT_HW + yo) * OUT_HW + xo) * 3;
    float a0, a1, a2;
    if (accumulate) {
        a0 = out[ob]; a1 = out[ob + 1]; a2 = out[ob + 2];
    } else {
        a0 = a1 = a2 = 0.f;
    }

    do_rounds<CSTART, CEND, CSTART>(agg, wlds, ilds, bk, tx, ty, a0, a1, a2);

    out[ob + 0] = a0; out[ob + 1] = a1; out[ob + 2] = a2;
}

// ---------------------------------------------------------------------------
// Host launch
// ---------------------------------------------------------------------------
extern "C" void kernel_launch(void* const* d_in, const int* in_sizes, int n_in,
                              void* d_out, int out_size, void* d_ws, size_t ws_size,
                              hipStream_t stream) {
    const float* x   = (const float*)d_in[0];
    const float* wp3 = (const float*)d_in[1];
    const float* wp4 = (const float*)d_in[2];
    const float* wp5 = (const float*)d_in[3];
    float* out = (float*)d_out;
    float4* wtbl = (float4*)d_ws;
    int*    itbl = (int*)((char*)d_ws + WTBL_BYTES);
    float4* wT   = (float4*)((char*)d_ws + WT_OFF_BYTES);
    uint2*  agg  = (uint2*)((char*)d_ws + AGG_OFF_BYTES);

    // Build the 21 configs exactly as the reference does (double precision).
    struct { int stride, size, nscale; double scales[3]; int gh; } layers[3] = {
        {32, 48, 2, {pow(2.0, 1.0 / 3.0), pow(2.0, 2.0 / 3.0), 0.0}, 14},
        {64, 96, 2, {pow(2.0, 1.0 / 3.0), pow(2.0, 2.0 / 3.0), 0.0}, 7},
        {128, 192, 3, {1.0, pow(2.0, 1.0 / 3.0), pow(2.0, 2.0 / 3.0)}, 4},
    };
    const double ars[3] = {0.667, 1.0, 1.5};

    struct HostCfg {
        int kh, kw, kwp, stride, p0, p1, gh, gw, layer, anchor, wt_off;
        int ns, blocks_per_img;
    } cfg[NCFG];
    TablesArgs ta;
    TrArgs tr;
    int nc = 0, wt_run = 0;
    for (int L = 0; L < 3; ++L) {
        int anchor = 0;
        for (int si = 0; si < layers[L].nscale; ++si) {
            for (int ai = 0; ai < 3; ++ai) {
                double ss = (double)layers[L].size * layers[L].scales[si];
                double sq = pow(ars[ai], 0.5);
                int kh = (int)(ss / sq);
                int kw = (int)(ss * sq);
                HostCfg& e = cfg[nc];
                e.kh = kh; e.kw = kw;
                e.kwp = kw + (kw & 1);
                e.stride = layers[L].stride;
                e.p0 = (int)ceil((double)(kh - layers[L].stride) / 2.0);
                e.p1 = (int)ceil((double)(kw - layers[L].stride) / 2.0);
                e.gh = layers[L].gh; e.gw = layers[L].gh;
                e.layer = L; e.anchor = anchor++;
                // strided-pair base-slot count per row
                int s = e.stride;
                int q = kw / s, r = kw % s;
                e.ns = ((q + 1) / 2) * s + ((q % 2 == 0) ? r : 0);
                e.blocks_per_img = (kh * e.ns + 255) / 256;
                e.wt_off = wt_run;
                int gsz = e.gh * e.gw;
                wt_run += BATCH * gsz;
                ta.kh[nc] = kh; ta.kw[nc] = kw;
                tr.layer[nc] = L; tr.anchor[nc] = e.anchor;
                tr.gsz[nc] = gsz; tr.wt_off[nc] = e.wt_off;
                ++nc;
            }
        }
    }

    init_tables<<<NCFG * 2, 256, 0, stream>>>(wtbl, itbl, ta);
    transpose_w<<<dim3(NCFG, BATCH), 256, 0, stream>>>(wp3, wp4, wp5, wT, tr);

    dim3 rgrid(OUT_HW / 16, OUT_HW / 16, BATCH * KK);

    // Static 3-group schedule: {0..14}, {15..18}, {19..20}.
    auto build = [&](int gstart, int gend, AggArgs& aa) -> int {
        aa.n = 0;
        int ablocks = 0;
        size_t off = 0;
        for (int c = gstart; c < gend; ++c) {
            ACfg& lc = aa.e[aa.n++];
            lc.kh = cfg[c].kh; lc.kw = cfg[c].kw; lc.kwp = cfg[c].kwp;
            lc.p0 = cfg[c].p0; lc.p1 = cfg[c].p1;
            lc.layer = cfg[c].layer;
            lc.ns = cfg[c].ns;
            lc.wt_off = cfg[c].wt_off;
            lc.ws_off = (int)off;
            lc.block_start = ablocks;
            lc.blocks_per_img = cfg[c].blocks_per_img;
            ablocks += cfg[c].blocks_per_img * BATCH;
            off += (size_t)cfg[c].kh * cfg[c].kwp * (BATCH * KK);
        }
        return ablocks;
    };

    AggArgs aa;
    int nb;

    nb = build(0, 15, aa);
    agg_all<<<nb, 256, 0, stream>>>(x, wT, agg, aa);
    resize_static<0, 15><<<rgrid, 256, 0, stream>>>(agg, wtbl, itbl, out, 0);

    nb = build(15, 19, aa);
    agg_all<<<nb, 256, 0, stream>>>(x, wT, agg, aa);
    resize_static<15, 19><<<rgrid, 256, 0, stream>>>(agg, wtbl, itbl, out, 1);

    nb = build(19, 21, aa);
    agg_all<<<nb, 256, 0, stream>>>(x, wT, agg, aa);
    resize_static<19, 21><<<rgrid, 256, 0, stream>>>(agg, wtbl, itbl, out, 1);

    (void)in_sizes; (void)n_in; (void)out_size; (void)ws_size;
}

// Round 7
// 265.975 us; speedup vs baseline: 1.2233x; 1.0221x over previous
//
#include <hip/hip_runtime.h>
#include <math.h>

// ---------------------------------------------------------------------------
// AttentionNet weighted-anchor aggregator.
//   x:  (8, 448, 448, 3) f32
//   wp3:(8, 6, 4, 14, 14) f32   wp4:(8, 6, 4, 7, 7) f32   wp5:(8, 9, 4, 4, 4) f32
//   out:(32, 224, 224, 3) f32 = sum over 21 configs of
//        resize_bilinear( einsum('bkij,bihjwc->bkhwc', w, patches), 224,224 )
//
// Phase 0a: init_tables — normalized zero-padded 4-tap weights + i0.
// Phase 0b: transpose_w — weights to [cfg][b][grid][k0..k3] float4.
// Phase A : agg_all — strided-pair mapping (r6), k-INTERLEAVED agg layout:
//           agg[...][px][k0..k3] (4 x uint2 = 32B per px). Epilogue = two
//           16B uint4 stores per px.
// Phase B : resize_static<CSTART,CEND> — 2 k-planes PER THREAD (z = b*2+kp).
//           Each tap = ONE 16B uint4 load (both k's), accumulated with
//           v_pk_fma over the k-pair. Halves load instructions + addr math,
//           doubles per-thread MLP: r6 resize was latency-bound (~3-5x above
//           both the VALU-issue and L2-BW floors at 3.2 waves/SIMD with <=9
//           outstanding 8B loads).
// GROUPS  : static {0..14}, {15..18}, {19..20}; agg stays <=68MB => L3-hot.
// ---------------------------------------------------------------------------

#define BATCH 8
#define KK 4
#define OUT_HW 224
#define IMG_HW 448
#define NCFG 21

#define WTBL_BYTES (NCFG * 2 * OUT_HW * 16)     // 150528
#define ITBL_BYTES (NCFG * 2 * OUT_HW * 4)      // 37632
#define WT_OFF_BYTES (WTBL_BYTES + ITBL_BYTES)  // 188160
#define WT_F4 12912                             // 8 * (6*196 + 6*49 + 9*16)
#define AGG_OFF_BYTES (WT_OFF_BYTES + WT_F4 * 16)  // 394752 (16B aligned)

typedef float v2f __attribute__((ext_vector_type(2)));

// Compile-time cfg geometry (== host double-precision construction; margins
// to int-truncation boundaries are >=0.05 so this is exact).
static constexpr int cKH[NCFG]  = {74,60,49,93,76,62, 148,120,98,186,152,124,
                                   235,192,156,296,241,197,373,304,248};
static constexpr int cKW[NCFG]  = {49,60,74,62,76,93, 98,120,148,124,152,186,
                                   156,192,235,197,241,296,248,304,373};
static constexpr int cMTH[NCFG] = {2,2,2,2,2,2, 2,2,2,2,2,2, 3,2,2,3,3,2,4,3,3};
static constexpr int cMTW[NCFG] = {2,2,2,2,2,2, 2,2,2,2,2,2, 2,2,3,2,3,3,3,3,4};

__host__ __device__ constexpr int ckwp(int c) { return cKW[c] + (cKW[c] & 1); }
// uint2-offset of cfg c's region within its group (layout [b][px][k]).
__host__ __device__ constexpr long cwsoff(int c, int g) {
    long o = 0;
    for (int k = g; k < c; ++k) o += (long)cKH[k] * ckwp(k) * (BATCH * KK);
    return o;
}

struct ACfg {              // agg view of a config
    int kh, kw, kwp, p0, p1;
    int layer;             // 0=p3, 1=p4, 2=p5
    int ns;                // base-slot count per row (strided pairing)
    int wt_off;            // float4 offset of transposed weights
    int ws_off;            // uint2 offset in agg region
    int block_start;
    int blocks_per_img;    // ceil(kh*ns/256)
};

struct AggArgs {
    ACfg e[NCFG];
    int n;
};

struct TablesArgs { int kh[NCFG]; int kw[NCFG]; };

struct TrArgs {
    int layer[NCFG];
    int anchor[NCFG];
    int gsz[NCFG];
    int wt_off[NCFG];
};

struct F3 { float a, b, c; };

__device__ inline unsigned int bf16_rne(float f) {
    unsigned int u = __float_as_uint(f);
    return (u + 0x7fffu + ((u >> 16) & 1u)) >> 16;
}

// ---------------------------------------------------------------------------
// Phase 0a: tap tables. jax.image.resize('bilinear', antialias=True):
//   inv=in/out; ks=max(inv,1); sf=(o+0.5)*inv-0.5; taps i in
//   [ceil(sf-ks), floor(sf+ks)] clamped, w=max(0,1-|i-sf|/ks) normalized.
// ---------------------------------------------------------------------------
__global__ __launch_bounds__(256) void init_tables(float4* __restrict__ wtbl,
                                                   int* __restrict__ itbl,
                                                   TablesArgs t) {
    int cfg = blockIdx.x >> 1;
    int dim = blockIdx.x & 1;
    int o = threadIdx.x;
    if (o >= OUT_HW) return;
    int n = dim ? t.kw[cfg] : t.kh[cfg];

    float inv = (float)(1.0 / ((double)OUT_HW / (double)n));
    float ks  = inv > 1.f ? inv : 1.f;
    float rks = 1.f / ks;
    float sf  = ((float)o + 0.5f) * inv - 0.5f;
    int i0 = (int)ceilf(sf - ks);  if (i0 < 0) i0 = 0;
    int i1 = (int)floorf(sf + ks); if (i1 > n - 1) i1 = n - 1;
    float sum = 0.f;
    for (int i = i0; i <= i1; ++i) {
        float v = 1.f - fabsf((float)i - sf) * rks;
        sum += (v > 0.f ? v : 0.f);
    }
    float rsum = 1.f / sum;
    float w[4];
#pragma unroll
    for (int d = 0; d < 4; ++d) {
        int i = i0 + d;
        float v = 0.f;
        if (i <= i1) {
            v = 1.f - fabsf((float)i - sf) * rks;
            v = (v > 0.f ? v : 0.f) * rsum;
        }
        w[d] = v;
    }
    int idx = cfg * (2 * OUT_HW) + dim * OUT_HW + o;
    wtbl[idx] = make_float4(w[0], w[1], w[2], w[3]);
    itbl[idx] = i0;
}

// ---------------------------------------------------------------------------
// Phase 0b: transpose weights (B,A,K,gh,gw) -> per cfg [b][g][k0..k3] float4.
// ---------------------------------------------------------------------------
__global__ __launch_bounds__(256) void transpose_w(
        const float* __restrict__ wp3, const float* __restrict__ wp4,
        const float* __restrict__ wp5, float4* __restrict__ wT, TrArgs t) {
    int cfg = blockIdx.x;
    int b = blockIdx.y;
    int gsz = t.gsz[cfg];
    const float* base;
    int A;
    if (t.layer[cfg] == 0)      { base = wp3; A = 6; }
    else if (t.layer[cfg] == 1) { base = wp4; A = 6; }
    else                        { base = wp5; A = 9; }
    const float* src = base + (size_t)(b * A + t.anchor[cfg]) * (KK * gsz);
    for (int g = threadIdx.x; g < gsz; g += 256) {
        wT[t.wt_off[cfg] + b * gsz + g] =
            make_float4(src[0 * gsz + g], src[1 * gsz + g],
                        src[2 * gsz + g], src[3 * gsz + g]);
    }
}

// ---------------------------------------------------------------------------
// Agg body: strided-pair outputs (w0, w0+STRIDE) packed as v2f lanes.
// Per row i: GW+1 clamped px loads (i-invariant offsets/masks), then GW
// j-steps of 12 v_pk_fma consuming (px[j], px[j+1]).
// Epilogue: k-interleaved [px][k0..k3] layout, two uint4 stores per px.
// ---------------------------------------------------------------------------
template <int GH, int GW, int STRIDE, int L2S>
__device__ inline void agg_body(const ACfg& c, int b, int h, int slot,
                                const float* __restrict__ xb,
                                const float4* __restrict__ wlds,
                                uint2* __restrict__ agg) {
    const int w0 = (((slot >> L2S) << (L2S + 1)) | (slot & (STRIDE - 1)));
    const int w1 = w0 + STRIDE;
    const bool two = w1 < c.kw;

    v2f acc2[4][3];
#pragma unroll
    for (int k = 0; k < 4; ++k)
#pragma unroll
        for (int ch = 0; ch < 3; ++ch) { acc2[k][ch].x = 0.f; acc2[k][ch].y = 0.f; }

    const int rb = h - c.p0;
    int ilo = rb >= 0 ? 0 : (-rb + STRIDE - 1) / STRIDE;
    int ihi = (IMG_HW - 1 - rb) / STRIDE;
    if (ihi > GH - 1) ihi = GH - 1;

    const int cb = w0 - c.p1;

    // i-invariant column offsets + validity masks
    int  cof[GW + 1];
    bool ok [GW + 1];
#pragma unroll
    for (int jj = 0; jj <= GW; ++jj) {
        int col = cb + jj * STRIDE;
        ok[jj] = (unsigned)col < (unsigned)IMG_HW;
        unsigned cc = (unsigned)col;
        if (cc > (unsigned)(IMG_HW - 1)) cc = (unsigned)(IMG_HW - 1);
        cof[jj] = (int)cc * 3;
    }

#pragma unroll 1
    for (int i = ilo; i <= ihi; ++i) {
        const float* xr = xb + (size_t)(rb + i * STRIDE) * (IMG_HW * 3);
        const float4* wrow = wlds + i * GW;

        float px[GW + 1][3];
#pragma unroll
        for (int jj = 0; jj <= GW; ++jj) {
            F3 v = *(const F3*)(xr + cof[jj]);
            px[jj][0] = ok[jj] ? v.a : 0.f;
            px[jj][1] = ok[jj] ? v.b : 0.f;
            px[jj][2] = ok[jj] ? v.c : 0.f;
        }

#pragma unroll
        for (int j = 0; j < GW; ++j) {
            float4 wk = wrow[j];
            v2f d0 = {px[j][0], px[j + 1][0]};
            v2f d1 = {px[j][1], px[j + 1][1]};
            v2f d2 = {px[j][2], px[j + 1][2]};
            v2f wv0 = {wk.x, wk.x};
            v2f wv1 = {wk.y, wk.y};
            v2f wv2 = {wk.z, wk.z};
            v2f wv3 = {wk.w, wk.w};
            acc2[0][0] = __builtin_elementwise_fma(wv0, d0, acc2[0][0]);
            acc2[0][1] = __builtin_elementwise_fma(wv0, d1, acc2[0][1]);
            acc2[0][2] = __builtin_elementwise_fma(wv0, d2, acc2[0][2]);
            acc2[1][0] = __builtin_elementwise_fma(wv1, d0, acc2[1][0]);
            acc2[1][1] = __builtin_elementwise_fma(wv1, d1, acc2[1][1]);
            acc2[1][2] = __builtin_elementwise_fma(wv1, d2, acc2[1][2]);
            acc2[2][0] = __builtin_elementwise_fma(wv2, d0, acc2[2][0]);
            acc2[2][1] = __builtin_elementwise_fma(wv2, d1, acc2[2][1]);
            acc2[2][2] = __builtin_elementwise_fma(wv2, d2, acc2[2][2]);
            acc2[3][0] = __builtin_elementwise_fma(wv3, d0, acc2[3][0]);
            acc2[3][1] = __builtin_elementwise_fma(wv3, d1, acc2[3][1]);
            acc2[3][2] = __builtin_elementwise_fma(wv3, d2, acc2[3][2]);
        }
    }

    const int npix = c.kh * c.kwp;
    // [px][k] interleaved: base uint2 index = (b*npix + h*kwp + w)*KK + k
    size_t pb0 = (size_t)c.ws_off
               + ((size_t)b * npix + (size_t)h * c.kwp + w0) * KK;
    {
        uint4 s0, s1;
        s0.x = bf16_rne(acc2[0][0].x) | (bf16_rne(acc2[0][1].x) << 16);
        s0.y = bf16_rne(acc2[0][2].x);
        s0.z = bf16_rne(acc2[1][0].x) | (bf16_rne(acc2[1][1].x) << 16);
        s0.w = bf16_rne(acc2[1][2].x);
        s1.x = bf16_rne(acc2[2][0].x) | (bf16_rne(acc2[2][1].x) << 16);
        s1.y = bf16_rne(acc2[2][2].x);
        s1.z = bf16_rne(acc2[3][0].x) | (bf16_rne(acc2[3][1].x) << 16);
        s1.w = bf16_rne(acc2[3][2].x);
        *(uint4*)(agg + pb0)     = s0;   // 32B-aligned base
        *(uint4*)(agg + pb0 + 2) = s1;
    }
    if (two) {
        size_t pb1 = pb0 + (size_t)STRIDE * KK;
        uint4 s0, s1;
        s0.x = bf16_rne(acc2[0][0].y) | (bf16_rne(acc2[0][1].y) << 16);
        s0.y = bf16_rne(acc2[0][2].y);
        s0.z = bf16_rne(acc2[1][0].y) | (bf16_rne(acc2[1][1].y) << 16);
        s0.w = bf16_rne(acc2[1][2].y);
        s1.x = bf16_rne(acc2[2][0].y) | (bf16_rne(acc2[2][1].y) << 16);
        s1.y = bf16_rne(acc2[2][2].y);
        s1.z = bf16_rne(acc2[3][0].y) | (bf16_rne(acc2[3][1].y) << 16);
        s1.w = bf16_rne(acc2[3][2].y);
        *(uint4*)(agg + pb1)     = s0;
        *(uint4*)(agg + pb1 + 2) = s1;
    }
}

// ---------------------------------------------------------------------------
// Phase A: one dispatch per group; block-uniform layer switch.
// b = local & 7: with round-robin block->XCD dispatch and 8 images == 8 XCDs,
// each XCD only ever touches one image (block_start is always 8-aligned).
// ---------------------------------------------------------------------------
__global__ __launch_bounds__(256, 3) void agg_all(
        const float* __restrict__ x,
        const float4* __restrict__ wT,
        uint2* __restrict__ agg,
        AggArgs a) {
    int bid = blockIdx.x;
    int ci = 0;
    while (ci + 1 < a.n && bid >= a.e[ci + 1].block_start) ci++;
    const ACfg c = a.e[ci];
    int local = bid - c.block_start;
    int b     = local & 7;           // image-per-XCD
    int sblk  = local >> 3;

    const int gsz = (c.layer == 0) ? 196 : (c.layer == 1) ? 49 : 16;
    __shared__ float4 wlds[196];
    for (int t = threadIdx.x; t < gsz; t += 256)
        wlds[t] = wT[c.wt_off + b * gsz + t];
    __syncthreads();

    int pidx = sblk * 256 + (int)threadIdx.x;
    if (pidx >= c.kh * c.ns) return;
    int h    = pidx / c.ns;
    int slot = pidx - h * c.ns;

    const float* __restrict__ xb = x + (size_t)b * (IMG_HW * IMG_HW * 3);
    if (c.layer == 0)      agg_body<14, 14, 32, 5>(c, b, h, slot, xb, wlds, agg);
    else if (c.layer == 1) agg_body<7, 7, 64, 6>(c, b, h, slot, xb, wlds, agg);
    else                   agg_body<4, 4, 128, 7>(c, b, h, slot, xb, wlds, agg);
}

// ---------------------------------------------------------------------------
// Tap micro-kernel, 2 k-planes per thread: each tap is ONE uint4 load
// (k-pair), accumulated with v_pk_fma. All TH*TW loads issued up-front.
// ---------------------------------------------------------------------------
template <int TH, int TW, int KH_, int KW_, int KWP_>
__device__ inline void taps_ct2(const uint2* __restrict__ pb,
                                int i0, int j0,
                                float4 wh4, float4 ww4,
                                v2f (&a)[3]) {
    const float* wh = (const float*)&wh4;
    const float* ww = (const float*)&ww4;
    uint4 v[TH][TW];
#pragma unroll
    for (int d = 0; d < TH; ++d) {
        int gi = i0 + d;
        if (gi > KH_ - 1) gi = KH_ - 1;
        const uint2* rp = pb + (size_t)gi * (KWP_ * KK);
#pragma unroll
        for (int e = 0; e < TW; ++e) {
            int gj = j0 + e;
            if (gj > KW_ - 1) gj = KW_ - 1;
            v[d][e] = *(const uint4*)(rp + gj * KK);
        }
    }
#pragma unroll
    for (int d = 0; d < TH; ++d) {
        v2f r0 = {0.f, 0.f}, r1 = {0.f, 0.f}, r2 = {0.f, 0.f};
#pragma unroll
        for (int e = 0; e < TW; ++e) {
            uint4 q = v[d][e];
            v2f c0, c1, c2;
            c0.x = __uint_as_float(q.x << 16);
            c0.y = __uint_as_float(q.z << 16);
            c1.x = __uint_as_float(q.x & 0xffff0000u);
            c1.y = __uint_as_float(q.z & 0xffff0000u);
            c2.x = __uint_as_float(q.y << 16);
            c2.y = __uint_as_float(q.w << 16);
            v2f w2 = {ww[e], ww[e]};
            r0 = __builtin_elementwise_fma(w2, c0, r0);
            r1 = __builtin_elementwise_fma(w2, c1, r1);
            r2 = __builtin_elementwise_fma(w2, c2, r2);
        }
        v2f h2 = {wh[d], wh[d]};
        a[0] = __builtin_elementwise_fma(h2, r0, a[0]);
        a[1] = __builtin_elementwise_fma(h2, r1, a[1]);
        a[2] = __builtin_elementwise_fma(h2, r2, a[2]);
    }
}

// ---------------------------------------------------------------------------
// if-constexpr recursion over the group's cfgs — fully unrolled rounds.
// ---------------------------------------------------------------------------
template <int C, int CEND, int CSTART>
__device__ inline void do_rounds(const uint2* __restrict__ agg,
                                 const float4* __restrict__ wlds,
                                 const int* __restrict__ ilds,
                                 int b, int kp, int tx, int ty,
                                 v2f (&a)[3]) {
    if constexpr (C < CEND) {
        constexpr int li  = C - CSTART;
        constexpr int kh  = cKH[C];
        constexpr int kw  = cKW[C];
        constexpr int kwp = ckwp(C);
        constexpr long wso = cwsoff(C, CSTART);
        float4 wh4 = wlds[li * 32 + ty];
        float4 ww4 = wlds[li * 32 + 16 + tx];
        int i0 = ilds[li * 32 + ty];
        int j0 = ilds[li * 32 + 16 + tx];
        const uint2* pb = agg + wso
                        + (size_t)b * ((size_t)kh * kwp * KK) + kp * 2;
        taps_ct2<cMTH[C], cMTW[C], kh, kw, kwp>(pb, i0, j0, wh4, ww4, a);
        do_rounds<C + 1, CEND, CSTART>(agg, wlds, ilds, b, kp, tx, ty, a);
    }
}

// ---------------------------------------------------------------------------
// Phase B: static resize, 2 k-planes per thread. z = b*2 + kp (16 planes).
// Tables in LDS (one barrier), all cfg rounds compile-time unrolled.
// ---------------------------------------------------------------------------
template <int CSTART, int CEND>
__global__ __launch_bounds__(256, 4) void resize_static(
        const uint2* __restrict__ agg,
        const float4* __restrict__ wtbl,
        const int* __restrict__ itbl,
        float* __restrict__ out,
        int accumulate) {
    constexpr int NC = CEND - CSTART;
    const int tid = threadIdx.x;
    const int tx = tid & 15;
    const int ty = tid >> 4;
    const int xo = blockIdx.x * 16 + tx;
    const int yo = blockIdx.y * 16 + ty;
    const int b  = blockIdx.z >> 1;
    const int kp = blockIdx.z & 1;

    __shared__ float4 wlds[NC * 32];
    __shared__ int    ilds[NC * 32];

    for (int e = tid; e < NC * 32; e += 256) {
        int ci  = e >> 5;
        int r   = e & 31;
        int isW = r >> 4;
        int idx = r & 15;
        int base_o = isW ? (blockIdx.x * 16) : (blockIdx.y * 16);
        int src = (CSTART + ci) * (2 * OUT_HW) + isW * OUT_HW + base_o + idx;
        wlds[ci * 32 + r] = wtbl[src];
        ilds[ci * 32 + r] = itbl[src];
    }
    __syncthreads();

    size_t obA = ((((size_t)(b * KK + kp * 2)) * OUT_HW + yo) * OUT_HW + xo) * 3;
    size_t obB = obA + (size_t)OUT_HW * OUT_HW * 3;

    v2f a[3];
    if (accumulate) {
        a[0].x = out[obA + 0]; a[0].y = out[obB + 0];
        a[1].x = out[obA + 1]; a[1].y = out[obB + 1];
        a[2].x = out[obA + 2]; a[2].y = out[obB + 2];
    } else {
        a[0] = v2f{0.f, 0.f}; a[1] = v2f{0.f, 0.f}; a[2] = v2f{0.f, 0.f};
    }

    do_rounds<CSTART, CEND, CSTART>(agg, wlds, ilds, b, kp, tx, ty, a);

    out[obA + 0] = a[0].x; out[obA + 1] = a[1].x; out[obA + 2] = a[2].x;
    out[obB + 0] = a[0].y; out[obB + 1] = a[1].y; out[obB + 2] = a[2].y;
}

// ---------------------------------------------------------------------------
// Host launch
// ---------------------------------------------------------------------------
extern "C" void kernel_launch(void* const* d_in, const int* in_sizes, int n_in,
                              void* d_out, int out_size, void* d_ws, size_t ws_size,
                              hipStream_t stream) {
    const float* x   = (const float*)d_in[0];
    const float* wp3 = (const float*)d_in[1];
    const float* wp4 = (const float*)d_in[2];
    const float* wp5 = (const float*)d_in[3];
    float* out = (float*)d_out;
    float4* wtbl = (float4*)d_ws;
    int*    itbl = (int*)((char*)d_ws + WTBL_BYTES);
    float4* wT   = (float4*)((char*)d_ws + WT_OFF_BYTES);
    uint2*  agg  = (uint2*)((char*)d_ws + AGG_OFF_BYTES);

    // Build the 21 configs exactly as the reference does (double precision).
    struct { int stride, size, nscale; double scales[3]; int gh; } layers[3] = {
        {32, 48, 2, {pow(2.0, 1.0 / 3.0), pow(2.0, 2.0 / 3.0), 0.0}, 14},
        {64, 96, 2, {pow(2.0, 1.0 / 3.0), pow(2.0, 2.0 / 3.0), 0.0}, 7},
        {128, 192, 3, {1.0, pow(2.0, 1.0 / 3.0), pow(2.0, 2.0 / 3.0)}, 4},
    };
    const double ars[3] = {0.667, 1.0, 1.5};

    struct HostCfg {
        int kh, kw, kwp, stride, p0, p1, gh, gw, layer, anchor, wt_off;
        int ns, blocks_per_img;
    } cfg[NCFG];
    TablesArgs ta;
    TrArgs tr;
    int nc = 0, wt_run = 0;
    for (int L = 0; L < 3; ++L) {
        int anchor = 0;
        for (int si = 0; si < layers[L].nscale; ++si) {
            for (int ai = 0; ai < 3; ++ai) {
                double ss = (double)layers[L].size * layers[L].scales[si];
                double sq = pow(ars[ai], 0.5);
                int kh = (int)(ss / sq);
                int kw = (int)(ss * sq);
                HostCfg& e = cfg[nc];
                e.kh = kh; e.kw = kw;
                e.kwp = kw + (kw & 1);
                e.stride = layers[L].stride;
                e.p0 = (int)ceil((double)(kh - layers[L].stride) / 2.0);
                e.p1 = (int)ceil((double)(kw - layers[L].stride) / 2.0);
                e.gh = layers[L].gh; e.gw = layers[L].gh;
                e.layer = L; e.anchor = anchor++;
                // strided-pair base-slot count per row
                int s = e.stride;
                int q = kw / s, r = kw % s;
                e.ns = ((q + 1) / 2) * s + ((q % 2 == 0) ? r : 0);
                e.blocks_per_img = (kh * e.ns + 255) / 256;
                e.wt_off = wt_run;
                int gsz = e.gh * e.gw;
                wt_run += BATCH * gsz;
                ta.kh[nc] = kh; ta.kw[nc] = kw;
                tr.layer[nc] = L; tr.anchor[nc] = e.anchor;
                tr.gsz[nc] = gsz; tr.wt_off[nc] = e.wt_off;
                ++nc;
            }
        }
    }

    init_tables<<<NCFG * 2, 256, 0, stream>>>(wtbl, itbl, ta);
    transpose_w<<<dim3(NCFG, BATCH), 256, 0, stream>>>(wp3, wp4, wp5, wT, tr);

    dim3 rgrid(OUT_HW / 16, OUT_HW / 16, BATCH * 2);

    // Static 3-group schedule: {0..14}, {15..18}, {19..20}.
    auto build = [&](int gstart, int gend, AggArgs& aa) -> int {
        aa.n = 0;
        int ablocks = 0;
        size_t off = 0;
        for (int c = gstart; c < gend; ++c) {
            ACfg& lc = aa.e[aa.n++];
            lc.kh = cfg[c].kh; lc.kw = cfg[c].kw; lc.kwp = cfg[c].kwp;
            lc.p0 = cfg[c].p0; lc.p1 = cfg[c].p1;
            lc.layer = cfg[c].layer;
            lc.ns = cfg[c].ns;
            lc.wt_off = cfg[c].wt_off;
            lc.ws_off = (int)off;
            lc.block_start = ablocks;
            lc.blocks_per_img = cfg[c].blocks_per_img;
            ablocks += cfg[c].blocks_per_img * BATCH;
            off += (size_t)cfg[c].kh * cfg[c].kwp * (BATCH * KK);
        }
        return ablocks;
    };

    AggArgs aa;
    int nb;

    nb = build(0, 15, aa);
    agg_all<<<nb, 256, 0, stream>>>(x, wT, agg, aa);
    resize_static<0, 15><<<rgrid, 256, 0, stream>>>(agg, wtbl, itbl, out, 0);

    nb = build(15, 19, aa);
    agg_all<<<nb, 256, 0, stream>>>(x, wT, agg, aa);
    resize_static<15, 19><<<rgrid, 256, 0, stream>>>(agg, wtbl, itbl, out, 1);

    nb = build(19, 21, aa);
    agg_all<<<nb, 256, 0, stream>>>(x, wT, agg, aa);
    resize_static<19, 21><<<rgrid, 256, 0, stream>>>(agg, wtbl, itbl, out, 1);

    (void)in_sizes; (void)n_in; (void)out_size; (void)ws_size;
}